// Round 7
// baseline (77.507 us; speedup 1.0000x reference)
//
#include <hip/hip_runtime.h>

#define BN_EPS 1e-5f

typedef unsigned short u16;
typedef __attribute__((ext_vector_type(8))) short bf16x8;
typedef __attribute__((ext_vector_type(4))) float f32x4;

__device__ __forceinline__ u16 f2bf(float x) {
  union { float f; unsigned int u; } v; v.f = x;
  unsigned int r = v.u + 0x7fffu + ((v.u >> 16) & 1u);
  return (u16)(r >> 16);
}
__device__ __forceinline__ float bf2f(u16 h) {
  union { unsigned int u; float f; } v; v.u = ((unsigned int)h) << 16;
  return v.f;
}

__device__ __forceinline__ float wave_reduce_sum(float v) {
#pragma unroll
  for (int off = 1; off < 64; off <<= 1) v += __shfl_xor(v, off, 64);
  return v;
}

// ---------------------------------------------------------------------------
// Kernel 1: embeddings -> fm_first (N x 576 bf16) + partial[n] (fp32), and
// (blocks >= NBE) W1 -> W1h bf16 padded to 512 rows (rows>=400 zero).
// ---------------------------------------------------------------------------
#define NBE 4096  // N/4 embed blocks
__global__ __launch_bounds__(256) void embed_prep(
    const float* __restrict__ Xi_dense, const float* __restrict__ Xv,
    const float* __restrict__ Wd, const float* __restrict__ bd,
    const float* __restrict__ tables, const int* __restrict__ Xi_cat,
    const float* __restrict__ bias_vec, const float* __restrict__ W1,
    u16* __restrict__ fm_first, float* __restrict__ partial,
    u16* __restrict__ W1h) {
  const int t = threadIdx.x;
  if (blockIdx.x >= NBE) {  // W1 conversion region: 512*576 = 72 blocks * 4096
    const int base = (blockIdx.x - NBE) * 4096;
#pragma unroll
    for (int e = 0; e < 16; ++e) {
      const int idx = base + e * 256 + t;
      const int r = idx / 576;
      const int j = idx - r * 576;
      W1h[idx] = (r < 400) ? f2bf(W1[r * 576 + j]) : (u16)0;
    }
    return;
  }
  const int lane = t & 63;
  const int n = blockIdx.x * 4 + (t >> 6);

  const float* xv = Xv + n * 36;
  float sum_all = 0.f, s_e = 0.f, q_e = 0.f;

#pragma unroll
  for (int k = 0; k < 9; ++k) {
    const int idx = lane + 64 * k;
    const int f = idx >> 4;
    const int e = idx & 15;
    float val;
    if (f < 26) {
      val = Xi_dense[n * 26 + f] * Wd[f * 16 + e] + bd[f * 16 + e];
    } else {
      const int fc = f - 26;
      const int row = Xi_cat[n * 10 + fc];
      val = tables[(size_t)fc * 200000 * 16 + (size_t)row * 16 + e];
    }
    val *= xv[f];
    fm_first[(size_t)n * 576 + idx] = f2bf(val);
    sum_all += val;
    s_e += val;
    q_e += val * val;
  }

  float s_tot = s_e;
  s_tot += __shfl_xor(s_tot, 16, 64);
  s_tot += __shfl_xor(s_tot, 32, 64);
  float q_tot = q_e;
  q_tot += __shfl_xor(q_tot, 16, 64);
  q_tot += __shfl_xor(q_tot, 32, 64);

  const float fm2 = 0.5f * (s_tot * s_tot - q_tot);  // replicated 4x per e
  const float red1 = wave_reduce_sum(sum_all);
  const float red2 = wave_reduce_sum(fm2) * 0.25f;
  if (lane == 0) partial[n] = red1 + red2 + bias_vec[n];
}

// ---------------------------------------------------------------------------
// B-stationary bf16 MFMA GEMM, barrier-free K-loop.
// Block = 256 rows x 64 cols, 4 waves; wave = 64 rows x 64 cols (4x4 frags).
// B panel (64 x K) staged ONCE into LDS (reg-staged, +8 elem pad -> balanced
// banks for ds_read_b128). A fragments load global->VGPR in MFMA-native
// layout (lanes lr,lr+16,lr+32,lr+48 consume one full 64B line), 2-deep
// prefetch. No barriers in the K-loop. Epilogue: bias + bf16 store +
// per-block column sum/sumsq partials (pS/pQ[col*64 + bx]).
// Grid = 64 x-panels x 7 col-tiles = 448 (%8==0), XCD-chunked swizzle.
// ---------------------------------------------------------------------------
template <int K>
__global__ __launch_bounds__(256) void gemm_bres(
    const u16* __restrict__ A,    // lda = K
    const u16* __restrict__ W,    // rows 0..447 valid (>=400 zero), ldw = K
    const float* __restrict__ bias, int nbias,
    u16* __restrict__ Y, int ldc, int Ncap,
    float* __restrict__ pS, float* __restrict__ pQ) {
  constexpr int NI = K / 32;     // K-steps
  constexpr int PADK = K + 8;    // padded LDS row stride (elements)
  constexpr int CPR = K / 8;     // 16B chunks per B row
  __shared__ u16 Bs[64 * PADK];
  __shared__ float rS[4][64];
  __shared__ float rQ[4][64];

  const int t = threadIdx.x;
  const int bid = blockIdx.x;
  const int l = (bid & 7) * 56 + (bid >> 3);  // XCD chunk swizzle (448 = 8*56)
  const int bx = l / 7;
  const int by = l - bx * 7;
  const int bm = bx * 256, bn = by * 64;

  // ---- stage B panel once (global -> reg -> padded LDS) ----
  for (int chunk = t; chunk < 64 * CPR; chunk += 256) {
    const int r = chunk / CPR;
    const int cc = (chunk - r * CPR) * 8;
    *(bf16x8*)&Bs[r * PADK + cc] =
        *(const bf16x8*)&W[(size_t)(bn + r) * K + cc];
  }
  __syncthreads();

  const int wid = t >> 6, lane = t & 63;
  const int lr = lane & 15, lk = (lane >> 4) * 8;
  const int rowb = bm + wid * 64;

  const u16* Ap = A + (size_t)(rowb + lr) * K + lk;  // + mf*16*K + kt

  f32x4 acc[4][4] = {};
  bf16x8 afA[4], afB[4];
#pragma unroll
  for (int mf = 0; mf < 4; ++mf) {
    afA[mf] = *(const bf16x8*)&Ap[(size_t)mf * 16 * K];
    afB[mf] = *(const bf16x8*)&Ap[(size_t)mf * 16 * K + 32];
  }

#pragma unroll
  for (int i = 0; i < NI; ++i) {
    const int kt = i * 32;
    bf16x8 bv[4];
#pragma unroll
    for (int nf = 0; nf < 4; ++nf)
      bv[nf] = *(const bf16x8*)&Bs[(nf * 16 + lr) * PADK + kt + lk];
    bf16x8 afN[4];
    if (i + 2 < NI) {
#pragma unroll
      for (int mf = 0; mf < 4; ++mf)
        afN[mf] = *(const bf16x8*)&Ap[(size_t)mf * 16 * K + kt + 64];
    } else {
#pragma unroll
      for (int mf = 0; mf < 4; ++mf) afN[mf] = afB[mf];
    }
    __builtin_amdgcn_s_setprio(1);
#pragma unroll
    for (int mf = 0; mf < 4; ++mf)
#pragma unroll
      for (int nf = 0; nf < 4; ++nf)
        acc[mf][nf] = __builtin_amdgcn_mfma_f32_16x16x32_bf16(
            afA[mf], bv[nf], acc[mf][nf], 0, 0, 0);
    __builtin_amdgcn_s_setprio(0);
#pragma unroll
    for (int mf = 0; mf < 4; ++mf) {
      afA[mf] = afB[mf];
      afB[mf] = afN[mf];
    }
  }

  // ---- epilogue: bias, bf16 store, per-block column stats ----
  const int l4 = (lane >> 4) * 4;
#pragma unroll
  for (int nf = 0; nf < 4; ++nf) {
    const int col = bn + nf * 16 + lr;
    const float bb = (col < nbias) ? bias[col] : 0.f;
    float s = 0.f, q = 0.f;
#pragma unroll
    for (int mf = 0; mf < 4; ++mf) {
#pragma unroll
      for (int r = 0; r < 4; ++r) {
        const int row = rowb + mf * 16 + l4 + r;
        const float v = acc[mf][nf][r] + bb;
        s += v;
        q += v * v;
        if (col < Ncap) Y[(size_t)row * ldc + col] = f2bf(v);
      }
    }
    s += __shfl_xor(s, 16, 64);
    s += __shfl_xor(s, 32, 64);
    q += __shfl_xor(q, 16, 64);
    q += __shfl_xor(q, 32, 64);
    if (lane < 16) {
      rS[wid][nf * 16 + lr] = s;
      rQ[wid][nf * 16 + lr] = q;
    }
  }
  __syncthreads();
  if (t < 64) {
    const float S = rS[0][t] + rS[1][t] + rS[2][t] + rS[3][t];
    const float Q = rQ[0][t] + rQ[1][t] + rQ[2][t] + rQ[3][t];
    pS[(size_t)(bn + t) * 64 + bx] = S;
    pQ[(size_t)(bn + t) * 64 + bx] = Q;
  }
}

// ---------------------------------------------------------------------------
// bn_ac: wave-per-column BN finalize. 100 blocks x 4 waves = 400 cols.
// ---------------------------------------------------------------------------
__global__ __launch_bounds__(256) void bn_ac(
    const float* __restrict__ pS, const float* __restrict__ pQ,
    const float* __restrict__ g, const float* __restrict__ be,
    float* __restrict__ a, float* __restrict__ c, int nxb) {
  const int wid = threadIdx.x >> 6, lane = threadIdx.x & 63;
  const int col = blockIdx.x * 4 + wid;  // grid=100 -> col<400
  float S = 0.f, Q = 0.f;
  for (int i = lane; i < nxb; i += 64) {
    S += pS[(size_t)col * nxb + i];
    Q += pQ[(size_t)col * nxb + i];
  }
#pragma unroll
  for (int off = 1; off < 64; off <<= 1) {
    S += __shfl_xor(S, off, 64);
    Q += __shfl_xor(Q, off, 64);
  }
  if (lane == 0) {
    const float mu = S * (1.f / 16384.f);
    const float var = Q * (1.f / 16384.f) - mu * mu;
    const float aa = g[col] * rsqrtf(var + BN_EPS);
    a[col] = aa;
    c[col] = be[col] - mu * aa;
  }
}

// ---------------------------------------------------------------------------
// prep2: fold BN1 affine into W2/b2 (a1/c1 from global, vectorized float4):
//   W2p[i][j] = bf16(W2[i][j] * a1[j])  (padded to 512 x 416, zeros beyond)
//   b2p[i]    = b2[i] + sum_j W2[i][j] * c1[j]
// ---------------------------------------------------------------------------
__global__ __launch_bounds__(256) void prep2(
    const float* __restrict__ a1, const float* __restrict__ c1,
    const float* __restrict__ W2, const float* __restrict__ b2,
    u16* __restrict__ W2p, float* __restrict__ b2p) {
  const int t = threadIdx.x;
  const int lane = t & 63;
  const int row = blockIdx.x * 4 + (t >> 6);
  const ushort4 z4 = {0, 0, 0, 0};
  if (row >= 400) {
    const int j1 = lane * 4;
    *(ushort4*)&W2p[(size_t)row * 416 + j1] = z4;
    const int j2 = 256 + lane * 4;
    if (j2 < 416) *(ushort4*)&W2p[(size_t)row * 416 + j2] = z4;
    if (lane == 0) b2p[row] = 0.f;
    return;
  }
  float dot = 0.f;
  {  // phase 1: j = lane*4 in [0,256)
    const int j = lane * 4;
    const float4 w = *(const float4*)&W2[(size_t)row * 400 + j];
    const float4 la = *(const float4*)&a1[j];
    const float4 lc = *(const float4*)&c1[j];
    ushort4 o = {f2bf(w.x * la.x), f2bf(w.y * la.y), f2bf(w.z * la.z),
                 f2bf(w.w * la.w)};
    *(ushort4*)&W2p[(size_t)row * 416 + j] = o;
    dot += w.x * lc.x + w.y * lc.y + w.z * lc.z + w.w * lc.w;
  }
  {  // phase 2: j = 256 + lane*4 in [256,512); real cols < 400, pad < 416
    const int j = 256 + lane * 4;
    if (j < 400) {
      const float4 w = *(const float4*)&W2[(size_t)row * 400 + j];
      const float4 la = *(const float4*)&a1[j];
      const float4 lc = *(const float4*)&c1[j];
      ushort4 o = {f2bf(w.x * la.x), f2bf(w.y * la.y), f2bf(w.z * la.z),
                   f2bf(w.w * la.w)};
      *(ushort4*)&W2p[(size_t)row * 416 + j] = o;
      dot += w.x * lc.x + w.y * lc.y + w.z * lc.z + w.w * lc.w;
    } else if (j < 416) {
      *(ushort4*)&W2p[(size_t)row * 416 + j] = z4;
    }
  }
  dot = wave_reduce_sum(dot);
  if (lane == 0) b2p[row] = b2[row] + dot;
}

// ---------------------------------------------------------------------------
// final: out[n] = partial[n] + sum_j (a2[j]*Y2[n,j] + c2[j])
// 1024 blocks x 4 waves x 4 rows. Lane owns cols [lane*8, lane*8+8).
// ---------------------------------------------------------------------------
__global__ __launch_bounds__(256) void final_kernel(
    const u16* __restrict__ Y2, const float* __restrict__ a2,
    const float* __restrict__ c2, const float* __restrict__ partial,
    float* __restrict__ out) {
  const int t = threadIdx.x;
  const int lane = t & 63;
  const int wid = t >> 6;
  const int j0 = lane * 8;
  float ar[8], cr[8];
  if (j0 < 400) {
    const float4 a0 = *(const float4*)&a2[j0];
    const float4 a1v = *(const float4*)&a2[j0 + 4];
    const float4 c0 = *(const float4*)&c2[j0];
    const float4 c1v = *(const float4*)&c2[j0 + 4];
    ar[0] = a0.x; ar[1] = a0.y; ar[2] = a0.z; ar[3] = a0.w;
    ar[4] = a1v.x; ar[5] = a1v.y; ar[6] = a1v.z; ar[7] = a1v.w;
    cr[0] = c0.x; cr[1] = c0.y; cr[2] = c0.z; cr[3] = c0.w;
    cr[4] = c1v.x; cr[5] = c1v.y; cr[6] = c1v.z; cr[7] = c1v.w;
  } else {
#pragma unroll
    for (int k = 0; k < 8; ++k) { ar[k] = 0.f; cr[k] = 0.f; }
  }
#pragma unroll
  for (int r = 0; r < 4; ++r) {
    const int n = blockIdx.x * 16 + wid * 4 + r;
    float acc = 0.f;
    if (j0 < 400) {
      const bf16x8 y = *(const bf16x8*)&Y2[(size_t)n * 400 + j0];
#pragma unroll
      for (int k = 0; k < 8; ++k)
        acc += fmaf(ar[k], bf2f((u16)y[k]), cr[k]);
    }
    acc = wave_reduce_sum(acc);
    if (lane == 0) out[n] = partial[n] + acc;
  }
}

extern "C" void kernel_launch(void* const* d_in, const int* in_sizes, int n_in,
                              void* d_out, int out_size, void* d_ws,
                              size_t ws_size, hipStream_t stream) {
  const float* Xi_dense = (const float*)d_in[0];
  const float* Xv = (const float*)d_in[1];
  const float* Wd = (const float*)d_in[2];
  const float* bd = (const float*)d_in[3];
  const float* tables = (const float*)d_in[4];
  const float* W1 = (const float*)d_in[5];
  const float* b1 = (const float*)d_in[6];
  const float* g1 = (const float*)d_in[7];
  const float* be1 = (const float*)d_in[8];
  const float* W2 = (const float*)d_in[9];
  const float* b2 = (const float*)d_in[10];
  const float* g2 = (const float*)d_in[11];
  const float* be2 = (const float*)d_in[12];
  const float* bias_vec = (const float*)d_in[13];
  const int* Xi_cat = (const int*)d_in[14];

  constexpr int N = 16384;
  constexpr int DIN = 576;
  constexpr int H = 400;
  constexpr int KP = 416;   // H padded to K-mult-of-32 for gemm2
  constexpr int WPAD = 512; // weight rows padded for staging reads
  constexpr int NXB = 64;   // gemm x-panels (N/256)

  u16* fm_first = (u16*)d_ws;                        // N*576
  u16* Y1h = fm_first + (size_t)N * DIN;             // N*416
  u16* Y2h = Y1h + (size_t)N * KP;                   // N*400
  u16* W1h = Y2h + (size_t)N * H;                    // 512*576
  u16* W2p = W1h + (size_t)WPAD * DIN;               // 512*416
  float* fptr = (float*)(W2p + (size_t)WPAD * KP);
  float* partial = fptr;                             // N
  float* pS = partial + N;                           // 448*64 (stride 64)
  float* pQ = pS + WPAD * NXB;
  float* a1 = pQ + WPAD * NXB;                       // 512
  float* c1 = a1 + WPAD;
  float* a2 = c1 + WPAD;
  float* c2 = a2 + WPAD;
  float* b2p = c2 + WPAD;                            // 512

  embed_prep<<<NBE + 72, 256, 0, stream>>>(Xi_dense, Xv, Wd, bd, tables,
                                           Xi_cat, bias_vec, W1, fm_first,
                                           partial, W1h);

  gemm_bres<DIN><<<NXB * 7, 256, 0, stream>>>(fm_first, W1h, b1, H,
                                              Y1h, KP, KP, pS, pQ);

  bn_ac<<<100, 256, 0, stream>>>(pS, pQ, g1, be1, a1, c1, NXB);
  prep2<<<128, 256, 0, stream>>>(a1, c1, W2, b2, W2p, b2p);

  gemm_bres<KP><<<NXB * 7, 256, 0, stream>>>(Y1h, W2p, b2p, H,
                                             Y2h, H, H, pS, pQ);

  bn_ac<<<100, 256, 0, stream>>>(pS, pQ, g2, be2, a2, c2, NXB);

  final_kernel<<<N / 16, 256, 0, stream>>>(Y2h, a2, c2, partial,
                                           (float*)d_out);
}